// Round 1
// baseline (215.328 us; speedup 1.0000x reference)
//
#include <hip/hip_runtime.h>
#include <hip/hip_bf16.h>

#define C_CLS   1000
#define U_PX    10
#define D_DIM   512
#define B_BATCH 4096
#define P_PX    (C_CLS * U_PX)     // 10000
#define ALPHA_F 32.0f
#define DELTA_F 0.1f

#define BM 64
#define BN 80        // 8 complete classes per tile
#define BK 64
#define LDA 72       // BK + 8 bf16 pad -> row stride 144 B (16B multiple, ~2-way conflicts = free)
#define SIMP 84      // padded sim_lds row (84*4 B: spreads banks for col-strided reads)

typedef __attribute__((ext_vector_type(8))) short bf16x8;
typedef __attribute__((ext_vector_type(4))) float f32x4;

__device__ __forceinline__ unsigned short f2bf(float f) {
    union { float f; unsigned u; } c; c.f = f;
    unsigned u = c.u;
    unsigned r = u + 0x7FFF + ((u >> 16) & 1);   // RN-even
    return (unsigned short)(r >> 16);
}

// ---------- row L2-normalize f32 -> bf16 (one block per row, 256 thr) ----------
__global__ __launch_bounds__(256) void norm_rows_kernel(const float* __restrict__ in,
                                                        unsigned int* __restrict__ out_packed) {
    const int row = blockIdx.x;
    const int t = threadIdx.x;
    const float2 v = reinterpret_cast<const float2*>(in + (size_t)row * D_DIM)[t];
    float ss = v.x * v.x + v.y * v.y;
    #pragma unroll
    for (int off = 32; off > 0; off >>= 1) ss += __shfl_down(ss, off, 64);
    __shared__ float part[4];
    if ((t & 63) == 0) part[t >> 6] = ss;
    __syncthreads();
    const float tot = part[0] + part[1] + part[2] + part[3];
    const float inv = 1.0f / fmaxf(sqrtf(tot), 1e-12f);
    const unsigned int lo = f2bf(v.x * inv), hi = f2bf(v.y * inv);
    out_packed[(size_t)row * (D_DIM / 2) + t] = lo | (hi << 16);
}

// ---------- fused GEMM + logits + loss partials ----------
__global__ __launch_bounds__(256) void fused_gemm_kernel(
    const unsigned short* __restrict__ xbf,   // [B][D] normalized bf16
    const unsigned short* __restrict__ pbf,   // [P][D] normalized bf16
    const int*            __restrict__ labels,
    float*                __restrict__ logits, // [B][C]
    float*                __restrict__ pos_sum, // [P]
    float*                __restrict__ neg_sum) // [P]
{
    __shared__ __align__(16) unsigned short A_lds[BM][LDA];
    __shared__ __align__(16) unsigned short B_lds[BN][LDA];
    __shared__ float sim_lds[BM][SIMP];
    __shared__ int   lab_lds[BM];

    const int t    = threadIdx.x;
    const int m0   = blockIdx.x * BM;
    const int n0   = blockIdx.y * BN;
    const int wid  = t >> 6;
    const int lane = t & 63;
    const int l15  = lane & 15;
    const int kgrp = lane >> 4;          // 0..3
    const int wrow = wid * 16;

    if (t < BM) lab_lds[t] = labels[m0 + t];

    f32x4 acc[5];
    #pragma unroll
    for (int n = 0; n < 5; ++n) acc[n] = (f32x4){0.f, 0.f, 0.f, 0.f};

    for (int ks = 0; ks < D_DIM / BK; ++ks) {
        const int kbase = ks * BK;
        __syncthreads();
        // stage A: 64 rows * 128B = 512 chunks of 16B, 2 per thread
        {
            int c = t;
            #pragma unroll
            for (int it = 0; it < 2; ++it) {
                const int row = c >> 3;
                const int off = (c & 7) * 8;      // bf16 elems
                const uint4 v = *reinterpret_cast<const uint4*>(
                    xbf + (size_t)(m0 + row) * D_DIM + kbase + off);
                *reinterpret_cast<uint4*>(&A_lds[row][off]) = v;
                c += 256;
            }
        }
        // stage B: 80 rows * 128B = 640 chunks of 16B
        for (int c = t; c < (BN * BK) / 8; c += 256) {
            const int row = c >> 3;
            const int off = (c & 7) * 8;
            const uint4 v = *reinterpret_cast<const uint4*>(
                pbf + (size_t)(n0 + row) * D_DIM + kbase + off);
            *reinterpret_cast<uint4*>(&B_lds[row][off]) = v;
        }
        __syncthreads();
        #pragma unroll
        for (int kk = 0; kk < BK; kk += 32) {
            const bf16x8 a = *reinterpret_cast<const bf16x8*>(&A_lds[wrow + l15][kk + kgrp * 8]);
            #pragma unroll
            for (int n = 0; n < 5; ++n) {
                const bf16x8 b = *reinterpret_cast<const bf16x8*>(&B_lds[n * 16 + l15][kk + kgrp * 8]);
                acc[n] = __builtin_amdgcn_mfma_f32_16x16x32_bf16(a, b, acc[n], 0, 0, 0);
            }
        }
    }

    // C/D layout (m89/m91): col = lane&15, row = (lane>>4)*4 + reg
    #pragma unroll
    for (int n = 0; n < 5; ++n)
        #pragma unroll
        for (int r = 0; r < 4; ++r)
            sim_lds[wrow + kgrp * 4 + r][n * 16 + l15] = acc[n][r];
    __syncthreads();

    // ---- logits: 64 rows x 8 classes = 512 (b,c) pairs, 2 per thread ----
    #pragma unroll
    for (int it = 0; it < 2; ++it) {
        const int j   = t + it * 256;
        const int row = j >> 3;
        const int c   = j & 7;
        const float* s = &sim_lds[row][c * U_PX];
        float wsum = 0.f, wssum = 0.f;
        #pragma unroll
        for (int u = 0; u < U_PX; ++u) {
            const float sv = s[u];
            const float e = __expf(sv);      // |s|<=1: no max-shift needed
            wsum += e; wssum += e * sv;
        }
        logits[(size_t)(m0 + row) * C_CLS + (n0 / U_PX + c)] = wssum / wsum;
    }

    // ---- loss partials: softplus(lse) == log1p(sum exp), so just exp-sums ----
    if (t < 160) {
        const int col = t % 80;
        const int seg = t / 80;              // 2 segments of 32 rows
        const int cls = (n0 + col) / U_PX;
        float posP = 0.f, negP = 0.f;
        #pragma unroll 8
        for (int r = seg * 32; r < seg * 32 + 32; ++r) {
            const float s = sim_lds[r][col];
            if (lab_lds[r] == cls) posP += __expf(-ALPHA_F * (s - DELTA_F));
            else                   negP += __expf( ALPHA_F * (s + DELTA_F));
        }
        atomicAdd(&neg_sum[n0 + col], negP);
        if (posP != 0.f) atomicAdd(&pos_sum[n0 + col], posP);
    }
}

// ---------- finalize: histogram -> has_pos, log1p reductions -> scalar loss ----------
__global__ __launch_bounds__(1024) void finalize_kernel(
    const int*   __restrict__ labels,
    const float* __restrict__ pos_sum,
    const float* __restrict__ neg_sum,
    float*       __restrict__ out_loss)
{
    __shared__ int   hist[C_CLS];
    __shared__ float sp[1024], sn[1024];
    __shared__ int   sc[1024];
    const int t = threadIdx.x;
    for (int i = t; i < C_CLS; i += 1024) hist[i] = 0;
    __syncthreads();
    for (int i = t; i < B_BATCH; i += 1024) atomicAdd(&hist[labels[i]], 1);
    __syncthreads();
    float pAcc = 0.f, nAcc = 0.f; int cnt = 0;
    for (int p = t; p < P_PX; p += 1024) {
        nAcc += log1pf(neg_sum[p]);
        if (hist[p / U_PX] > 0) { pAcc += log1pf(pos_sum[p]); cnt++; }
    }
    sp[t] = pAcc; sn[t] = nAcc; sc[t] = cnt;
    __syncthreads();
    for (int s = 512; s > 0; s >>= 1) {
        if (t < s) { sp[t] += sp[t + s]; sn[t] += sn[t + s]; sc[t] += sc[t + s]; }
        __syncthreads();
    }
    if (t == 0)
        out_loss[0] = sp[0] / (float)max(sc[0], 1) + sn[0] / (float)P_PX;
}

extern "C" void kernel_launch(void* const* d_in, const int* in_sizes, int n_in,
                              void* d_out, int out_size, void* d_ws, size_t ws_size,
                              hipStream_t stream) {
    const float* features = (const float*)d_in[0];
    const int*   labels   = (const int*)d_in[1];
    const float* proxies  = (const float*)d_in[2];
    float* out = (float*)d_out;              // [B*C] logits, then [1] loss

    char* ws = (char*)d_ws;
    unsigned short* xbf = (unsigned short*)ws;                               // 4 MiB
    unsigned short* pbf = (unsigned short*)(ws + (size_t)B_BATCH * D_DIM * 2); // 10 MiB
    float* pos_sum = (float*)(ws + (size_t)(B_BATCH + P_PX) * D_DIM * 2);
    float* neg_sum = pos_sum + P_PX;

    hipMemsetAsync(pos_sum, 0, 2 * P_PX * sizeof(float), stream);

    norm_rows_kernel<<<B_BATCH, 256, 0, stream>>>(features, (unsigned int*)xbf);
    norm_rows_kernel<<<P_PX,   256, 0, stream>>>(proxies,  (unsigned int*)pbf);

    fused_gemm_kernel<<<dim3(B_BATCH / BM, P_PX / BN), 256, 0, stream>>>(
        xbf, pbf, labels, out, pos_sum, neg_sum);

    finalize_kernel<<<1, 1024, 0, stream>>>(labels, pos_sum, neg_sum,
                                            out + (size_t)B_BATCH * C_CLS);
}

// Round 2
// 137.573 us; speedup vs baseline: 1.5652x; 1.5652x over previous
//
#include <hip/hip_runtime.h>
#include <hip/hip_bf16.h>

#define C_CLS   1000
#define U_PX    10
#define D_DIM   512
#define B_BATCH 4096
#define P_PX    (C_CLS * U_PX)     // 10000
#define ALPHA_F 32.0f
#define DELTA_F 0.1f

#define BM 128
#define BN 80        // 8 complete classes per tile; 10000/80 = 125
#define BK 64        // 128 B per LDS row, linear (global_load_lds dest)
#define SIMP 84      // padded sim row in f32

// LDS byte layout: A [128 rows][128 B] at 0 (16 KiB), B [80 rows][128 B] at 16384 (10 KiB).
// After K-loop the same buffer is reused as float sim[128][84] (43008 B).
#define A_OFF   0
#define B_OFF   16384
#define SMEM_SZ 43008

typedef __attribute__((ext_vector_type(8))) short bf16x8;
typedef __attribute__((ext_vector_type(4))) float f32x4;

typedef __attribute__((address_space(1))) const void gv_t;
typedef __attribute__((address_space(3))) void lv_t;

__device__ __forceinline__ void gload_lds16(const void* g, void* lds) {
    __builtin_amdgcn_global_load_lds((gv_t*)g, (lv_t*)lds, 16, 0, 0);
}

__device__ __forceinline__ unsigned short f2bf(float f) {
    union { float f; unsigned u; } c; c.f = f;
    unsigned u = c.u;
    unsigned r = u + 0x7FFF + ((u >> 16) & 1);   // RN-even
    return (unsigned short)(r >> 16);
}

// ---------- row L2-normalize f32 -> bf16, both inputs in one grid ----------
__global__ __launch_bounds__(256) void norm_rows_kernel(const float* __restrict__ feat,
                                                        const float* __restrict__ prox,
                                                        unsigned int* __restrict__ xout,
                                                        unsigned int* __restrict__ pout) {
    int row = blockIdx.x;
    const float* in;
    unsigned int* out;
    if (row < B_BATCH) { in = feat + (size_t)row * D_DIM;              out = xout + (size_t)row * (D_DIM / 2); }
    else { row -= B_BATCH; in = prox + (size_t)row * D_DIM;            out = pout + (size_t)row * (D_DIM / 2); }
    const int t = threadIdx.x;
    const float2 v = reinterpret_cast<const float2*>(in)[t];
    float ss = v.x * v.x + v.y * v.y;
    #pragma unroll
    for (int off = 32; off > 0; off >>= 1) ss += __shfl_down(ss, off, 64);
    __shared__ float part[4];
    if ((t & 63) == 0) part[t >> 6] = ss;
    __syncthreads();
    const float tot = part[0] + part[1] + part[2] + part[3];
    const float inv = 1.0f / fmaxf(sqrtf(tot), 1e-12f);
    const unsigned int lo = f2bf(v.x * inv), hi = f2bf(v.y * inv);
    out[t] = lo | (hi << 16);
}

// ---------- fused GEMM + logits + loss partials ----------
__global__ __launch_bounds__(256) void fused_gemm_kernel(
    const unsigned short* __restrict__ xbf,   // [B][D] normalized bf16
    const unsigned short* __restrict__ pbf,   // [P][D] normalized bf16
    const int*            __restrict__ labels,
    float*                __restrict__ logits, // [B][C]
    float*                __restrict__ pos_sum, // [P]
    float*                __restrict__ neg_sum) // [P]
{
    __shared__ __align__(16) char smem[SMEM_SZ];
    __shared__ int lab_lds[BM];

    const int t    = threadIdx.x;
    const int m0   = blockIdx.x * BM;
    const int n0   = blockIdx.y * BN;
    const int wid  = t >> 6;
    const int lane = t & 63;
    const int l15  = lane & 15;
    const int kgrp = lane >> 4;          // 0..3
    const int swzA = (l15 & 7) << 4;     // read-side XOR (row&7)<<4; row&7 == l15&7 here

    if (t < BM) lab_lds[t] = labels[m0 + t];

    // source pre-swizzle for linear global_load_lds dest (rule #21):
    // within each 1KiB chunk (8 rows of 128B), lane l writes LDS (row=l>>3, c16=l&7)
    // and must fetch global chunk (l&7) ^ (l>>3)  [row&7 == l>>3 since r0 % 8 == 0]
    const int srow  = lane >> 3;                 // 0..7 within chunk
    const int scol  = (lane & 7) ^ srow;         // swizzled 16B-chunk index

    f32x4 acc[2][5];
    #pragma unroll
    for (int m = 0; m < 2; ++m)
        #pragma unroll
        for (int n = 0; n < 5; ++n) acc[m][n] = (f32x4){0.f, 0.f, 0.f, 0.f};

    for (int ks = 0; ks < D_DIM / BK; ++ks) {
        const int kbase = ks * BK;
        // ---- stage: 16 A-chunks + 10 B-chunks of 1KiB, round-robin over waves ----
        for (int c = wid; c < 26; c += 4) {
            if (c < 16) {
                const int row = c * 8 + srow;
                gload_lds16(xbf + (size_t)(m0 + row) * D_DIM + kbase + scol * 8,
                            smem + A_OFF + c * 1024);
            } else {
                const int row = (c - 16) * 8 + srow;
                gload_lds16(pbf + (size_t)(n0 + row) * D_DIM + kbase + scol * 8,
                            smem + B_OFF + (c - 16) * 1024);
            }
        }
        __syncthreads();   // compiler drains vmcnt(0) before barrier
        // ---- compute ----
        #pragma unroll
        for (int kk8 = 0; kk8 < 2; ++kk8) {          // 32 elems (64 B) per sub-step
            const int kByte = kk8 * 64 + kgrp * 16;
            bf16x8 a[2], b[5];
            #pragma unroll
            for (int m = 0; m < 2; ++m) {
                const int row = wid * 32 + m * 16 + l15;
                a[m] = *reinterpret_cast<const bf16x8*>(smem + A_OFF + row * 128 + (kByte ^ swzA));
            }
            #pragma unroll
            for (int n = 0; n < 5; ++n) {
                const int row = n * 16 + l15;
                b[n] = *reinterpret_cast<const bf16x8*>(smem + B_OFF + row * 128 + (kByte ^ swzA));
            }
            #pragma unroll
            for (int m = 0; m < 2; ++m)
                #pragma unroll
                for (int n = 0; n < 5; ++n)
                    acc[m][n] = __builtin_amdgcn_mfma_f32_16x16x32_bf16(a[m], b[n], acc[m][n], 0, 0, 0);
        }
        __syncthreads();   // all reads done before next stage overwrites
    }

    // ---- dump sim tile into (reused) LDS; C/D layout: col=lane&15, row=(lane>>4)*4+reg ----
    float (*sim)[SIMP] = (float(*)[SIMP])smem;
    #pragma unroll
    for (int m = 0; m < 2; ++m)
        #pragma unroll
        for (int n = 0; n < 5; ++n)
            #pragma unroll
            for (int r = 0; r < 4; ++r)
                sim[wid * 32 + m * 16 + kgrp * 4 + r][n * 16 + l15] = acc[m][n][r];
    __syncthreads();

    // ---- logits: 128 rows x 8 classes = 1024 pairs, 4 per thread ----
    #pragma unroll
    for (int it = 0; it < 4; ++it) {
        const int j   = t + it * 256;
        const int row = j >> 3;
        const int c   = j & 7;
        const float* s = &sim[row][c * U_PX];
        float wsum = 0.f, wssum = 0.f;
        #pragma unroll
        for (int u = 0; u < U_PX; ++u) {
            const float sv = s[u];
            const float e = __expf(sv);      // |s|<=1: no max-shift needed
            wsum += e; wssum += e * sv;
        }
        logits[(size_t)(m0 + row) * C_CLS + (n0 / U_PX + c)] = wssum / wsum;
    }

    // ---- loss partials: softplus(lse) == log1p(sum exp) -> plain exp-sums ----
    if (t < 160) {
        const int col = t % 80;
        const int seg = t / 80;              // 2 segments of 64 rows
        const int cls = (n0 + col) / U_PX;
        float posP = 0.f, negP = 0.f;
        #pragma unroll 8
        for (int r = seg * 64; r < seg * 64 + 64; ++r) {
            const float s = sim[r][col];
            if (lab_lds[r] == cls) posP += __expf(-ALPHA_F * (s - DELTA_F));
            else                   negP += __expf( ALPHA_F * (s + DELTA_F));
        }
        atomicAdd(&neg_sum[n0 + col], negP);
        if (posP != 0.f) atomicAdd(&pos_sum[n0 + col], posP);
    }
}

// ---------- finalize: histogram -> has_pos, log1p reductions -> scalar loss ----------
__global__ __launch_bounds__(1024) void finalize_kernel(
    const int*   __restrict__ labels,
    const float* __restrict__ pos_sum,
    const float* __restrict__ neg_sum,
    float*       __restrict__ out_loss)
{
    __shared__ int   hist[C_CLS];
    __shared__ float sp[1024], sn[1024];
    __shared__ int   sc[1024];
    const int t = threadIdx.x;
    for (int i = t; i < C_CLS; i += 1024) hist[i] = 0;
    __syncthreads();
    for (int i = t; i < B_BATCH; i += 1024) atomicAdd(&hist[labels[i]], 1);
    __syncthreads();
    float pAcc = 0.f, nAcc = 0.f; int cnt = 0;
    for (int p = t; p < P_PX; p += 1024) {
        nAcc += log1pf(neg_sum[p]);
        if (hist[p / U_PX] > 0) { pAcc += log1pf(pos_sum[p]); cnt++; }
    }
    sp[t] = pAcc; sn[t] = nAcc; sc[t] = cnt;
    __syncthreads();
    for (int s = 512; s > 0; s >>= 1) {
        if (t < s) { sp[t] += sp[t + s]; sn[t] += sn[t + s]; sc[t] += sc[t + s]; }
        __syncthreads();
    }
    if (t == 0)
        out_loss[0] = sp[0] / (float)max(sc[0], 1) + sn[0] / (float)P_PX;
}

extern "C" void kernel_launch(void* const* d_in, const int* in_sizes, int n_in,
                              void* d_out, int out_size, void* d_ws, size_t ws_size,
                              hipStream_t stream) {
    const float* features = (const float*)d_in[0];
    const int*   labels   = (const int*)d_in[1];
    const float* proxies  = (const float*)d_in[2];
    float* out = (float*)d_out;              // [B*C] logits, then [1] loss

    char* ws = (char*)d_ws;
    unsigned short* xbf = (unsigned short*)ws;                                 // 4 MiB
    unsigned short* pbf = (unsigned short*)(ws + (size_t)B_BATCH * D_DIM * 2); // 10 MiB
    float* pos_sum = (float*)(ws + (size_t)(B_BATCH + P_PX) * D_DIM * 2);
    float* neg_sum = pos_sum + P_PX;

    hipMemsetAsync(pos_sum, 0, 2 * P_PX * sizeof(float), stream);

    norm_rows_kernel<<<B_BATCH + P_PX, 256, 0, stream>>>(
        features, proxies, (unsigned int*)xbf, (unsigned int*)pbf);

    fused_gemm_kernel<<<dim3(B_BATCH / BM, P_PX / BN), 256, 0, stream>>>(
        xbf, pbf, labels, out, pos_sum, neg_sum);

    finalize_kernel<<<1, 1024, 0, stream>>>(labels, pos_sum, neg_sum,
                                            out + (size_t)B_BATCH * C_CLS);
}

// Round 3
// 135.422 us; speedup vs baseline: 1.5901x; 1.0159x over previous
//
#include <hip/hip_runtime.h>
#include <hip/hip_bf16.h>

#define C_CLS   1000
#define U_PX    10
#define D_DIM   512
#define B_BATCH 4096
#define P_PX    (C_CLS * U_PX)     // 10000
#define ALPHA_F 32.0f
#define DELTA_F 0.1f

#define BM 128
#define BN 80        // 8 complete classes per tile; 10000/80 = 125
#define BK 64        // 128 B per LDS row, linear (global_load_lds dest)
#define SIMP 84      // padded sim row in f32

// Double-buffered LDS: per buffer A [128][128B] (16K) + B [80][128B] (10K) = 26624 B.
// buf0 @ 0, buf1 @ 26624. After K-loop the region is reused as float sim[128][84].
#define A_OFF    0
#define B_OFF    16384
#define BUF_STRIDE 26624
#define SMEM_SZ  (2 * BUF_STRIDE)   // 53248 >= sim 43008

typedef __attribute__((ext_vector_type(8))) short bf16x8;
typedef __attribute__((ext_vector_type(4))) float f32x4;

typedef __attribute__((address_space(1))) const void gv_t;
typedef __attribute__((address_space(3))) void lv_t;

__device__ __forceinline__ void gload_lds16(const void* g, void* lds) {
    __builtin_amdgcn_global_load_lds((gv_t*)g, (lv_t*)lds, 16, 0, 0);
}

__device__ __forceinline__ unsigned short f2bf(float f) {
    union { float f; unsigned u; } c; c.f = f;
    unsigned u = c.u;
    unsigned r = u + 0x7FFF + ((u >> 16) & 1);   // RN-even
    return (unsigned short)(r >> 16);
}

// ---------- row L2-normalize f32 -> bf16, both inputs in one grid ----------
__global__ __launch_bounds__(256) void norm_rows_kernel(const float* __restrict__ feat,
                                                        const float* __restrict__ prox,
                                                        unsigned int* __restrict__ xout,
                                                        unsigned int* __restrict__ pout) {
    int row = blockIdx.x;
    const float* in;
    unsigned int* out;
    if (row < B_BATCH) { in = feat + (size_t)row * D_DIM;   out = xout + (size_t)row * (D_DIM / 2); }
    else { row -= B_BATCH; in = prox + (size_t)row * D_DIM; out = pout + (size_t)row * (D_DIM / 2); }
    const int t = threadIdx.x;
    const float2 v = reinterpret_cast<const float2*>(in)[t];
    float ss = v.x * v.x + v.y * v.y;
    #pragma unroll
    for (int off = 32; off > 0; off >>= 1) ss += __shfl_down(ss, off, 64);
    __shared__ float part[4];
    if ((t & 63) == 0) part[t >> 6] = ss;
    __syncthreads();
    const float tot = part[0] + part[1] + part[2] + part[3];
    const float inv = 1.0f / fmaxf(sqrtf(tot), 1e-12f);
    const unsigned int lo = f2bf(v.x * inv), hi = f2bf(v.y * inv);
    out[t] = lo | (hi << 16);
}

// ---------- fused GEMM + logits + loss partials ----------
__global__ __launch_bounds__(256) void fused_gemm_kernel(
    const unsigned short* __restrict__ xbf,   // [B][D] normalized bf16
    const unsigned short* __restrict__ pbf,   // [P][D] normalized bf16
    const int*            __restrict__ labels,
    float*                __restrict__ logits, // [B][C]
    float*                __restrict__ pos_sum, // [P]
    float*                __restrict__ neg_sum) // [P]
{
    __shared__ __align__(16) char smem[SMEM_SZ];
    __shared__ int lab_lds[BM];

    const int t    = threadIdx.x;
    const int m0   = blockIdx.x * BM;
    const int n0   = blockIdx.y * BN;
    const int wid  = t >> 6;
    const int lane = t & 63;
    const int l15  = lane & 15;
    const int kgrp = lane >> 4;          // 0..3
    const int swzA = (l15 & 7) << 4;     // read-side XOR (row&7)<<4

    if (t < BM) lab_lds[t] = labels[m0 + t];

    // source pre-swizzle for linear global_load_lds dest (rule #21):
    // within each 1KiB chunk (8 rows of 128B), lane l writes LDS (row=l>>3, c16=l&7)
    // and must fetch global chunk (l&7) ^ (l>>3)
    const int srow  = lane >> 3;                 // 0..7 within chunk
    const int scol  = (lane & 7) ^ srow;         // swizzled 16B-chunk index

    f32x4 acc[2][5];
    #pragma unroll
    for (int m = 0; m < 2; ++m)
        #pragma unroll
        for (int n = 0; n < 5; ++n) acc[m][n] = (f32x4){0.f, 0.f, 0.f, 0.f};

    // ---- staging helper (round-robin over waves): 16 A-chunks + 10 B-chunks of 1KiB ----
    #define STAGE(ks_, buf_)                                                            \
        do {                                                                            \
            const int kb_ = (ks_) * BK;                                                 \
            char* base_ = smem + (buf_) * BUF_STRIDE;                                   \
            for (int c = wid; c < 26; c += 4) {                                         \
                if (c < 16) {                                                           \
                    const int row = c * 8 + srow;                                       \
                    gload_lds16(xbf + (size_t)(m0 + row) * D_DIM + kb_ + scol * 8,      \
                                base_ + A_OFF + c * 1024);                              \
                } else {                                                                \
                    const int row = (c - 16) * 8 + srow;                                \
                    gload_lds16(pbf + (size_t)(n0 + row) * D_DIM + kb_ + scol * 8,      \
                                base_ + B_OFF + (c - 16) * 1024);                       \
                }                                                                       \
            }                                                                           \
        } while (0)

    STAGE(0, 0);
    __syncthreads();

    for (int ks = 0; ks < D_DIM / BK; ++ks) {
        const int cur = ks & 1;
        if (ks < D_DIM / BK - 1) STAGE(ks + 1, cur ^ 1);   // issue next-tile loads first
        const char* base = smem + cur * BUF_STRIDE;
        #pragma unroll
        for (int kk8 = 0; kk8 < 2; ++kk8) {                // 32 elems (64 B) per sub-step
            const int kByte = kk8 * 64 + kgrp * 16;
            bf16x8 a[2], b[5];
            #pragma unroll
            for (int m = 0; m < 2; ++m) {
                const int row = wid * 32 + m * 16 + l15;
                a[m] = *reinterpret_cast<const bf16x8*>(base + A_OFF + row * 128 + (kByte ^ swzA));
            }
            #pragma unroll
            for (int n = 0; n < 5; ++n) {
                const int row = n * 16 + l15;
                b[n] = *reinterpret_cast<const bf16x8*>(base + B_OFF + row * 128 + (kByte ^ swzA));
            }
            #pragma unroll
            for (int m = 0; m < 2; ++m)
                #pragma unroll
                for (int n = 0; n < 5; ++n)
                    acc[m][n] = __builtin_amdgcn_mfma_f32_16x16x32_bf16(a[m], b[n], acc[m][n], 0, 0, 0);
        }
        __syncthreads();   // drains vmcnt(0): next buffer staged; cur buffer reads done
    }

    // ---- loss partials fully in-register ----
    // lane holds sim(row = wid*32 + m*16 + kgrp*4 + r, col = n*16 + l15) in acc[m][n][r]
    {
        int labv[8];
        #pragma unroll
        for (int m = 0; m < 2; ++m)
            #pragma unroll
            for (int r = 0; r < 4; ++r)
                labv[m * 4 + r] = lab_lds[wid * 32 + m * 16 + kgrp * 4 + r];
        #pragma unroll
        for (int n = 0; n < 5; ++n) {
            const int col = n * 16 + l15;
            const int cls = (n0 + col) / U_PX;
            float pos = 0.f, neg = 0.f;
            #pragma unroll
            for (int m = 0; m < 2; ++m)
                #pragma unroll
                for (int r = 0; r < 4; ++r) {
                    const float s = acc[m][n][r];
                    const bool isp = (labv[m * 4 + r] == cls);
                    const float e = __expf(isp ? (-ALPHA_F * (s - DELTA_F))
                                               : ( ALPHA_F * (s + DELTA_F)));
                    if (isp) pos += e; else neg += e;
                }
            // reduce across the 4 kgrp lanes holding the same column (xor 16, 32)
            pos += __shfl_xor(pos, 16, 64); pos += __shfl_xor(pos, 32, 64);
            neg += __shfl_xor(neg, 16, 64); neg += __shfl_xor(neg, 32, 64);
            if (lane < 16) {
                atomicAdd(&neg_sum[n0 + col], neg);
                if (pos != 0.f) atomicAdd(&pos_sum[n0 + col], pos);
            }
        }
    }

    // ---- dump sim tile into (reused) LDS; C/D layout: col=lane&15, row=(lane>>4)*4+reg ----
    float (*sim)[SIMP] = (float(*)[SIMP])smem;
    #pragma unroll
    for (int m = 0; m < 2; ++m)
        #pragma unroll
        for (int n = 0; n < 5; ++n)
            #pragma unroll
            for (int r = 0; r < 4; ++r)
                sim[wid * 32 + m * 16 + kgrp * 4 + r][n * 16 + l15] = acc[m][n][r];
    __syncthreads();

    // ---- logits: 128 rows x 8 classes = 1024 pairs, 4 per thread ----
    #pragma unroll
    for (int it = 0; it < 4; ++it) {
        const int j   = t + it * 256;
        const int row = j >> 3;
        const int c   = j & 7;
        const float* s = &sim[row][c * U_PX];
        float wsum = 0.f, wssum = 0.f;
        #pragma unroll
        for (int u = 0; u < U_PX; ++u) {
            const float sv = s[u];
            const float e = __expf(sv);      // |s|<=1: no max-shift needed
            wsum += e; wssum += e * sv;
        }
        logits[(size_t)(m0 + row) * C_CLS + (n0 / U_PX + c)] = wssum / wsum;
    }
}

// ---------- finalize: histogram -> has_pos, log1p reductions -> scalar loss ----------
__global__ __launch_bounds__(1024) void finalize_kernel(
    const int*   __restrict__ labels,
    const float* __restrict__ pos_sum,
    const float* __restrict__ neg_sum,
    float*       __restrict__ out_loss)
{
    __shared__ int   hist[C_CLS];
    __shared__ float sp[1024], sn[1024];
    __shared__ int   sc[1024];
    const int t = threadIdx.x;
    for (int i = t; i < C_CLS; i += 1024) hist[i] = 0;
    __syncthreads();
    for (int i = t; i < B_BATCH; i += 1024) atomicAdd(&hist[labels[i]], 1);
    __syncthreads();
    float pAcc = 0.f, nAcc = 0.f; int cnt = 0;
    for (int p = t; p < P_PX; p += 1024) {
        nAcc += log1pf(neg_sum[p]);
        if (hist[p / U_PX] > 0) { pAcc += log1pf(pos_sum[p]); cnt++; }
    }
    sp[t] = pAcc; sn[t] = nAcc; sc[t] = cnt;
    __syncthreads();
    for (int s = 512; s > 0; s >>= 1) {
        if (t < s) { sp[t] += sp[t + s]; sn[t] += sn[t + s]; sc[t] += sc[t + s]; }
        __syncthreads();
    }
    if (t == 0)
        out_loss[0] = sp[0] / (float)max(sc[0], 1) + sn[0] / (float)P_PX;
}

extern "C" void kernel_launch(void* const* d_in, const int* in_sizes, int n_in,
                              void* d_out, int out_size, void* d_ws, size_t ws_size,
                              hipStream_t stream) {
    const float* features = (const float*)d_in[0];
    const int*   labels   = (const int*)d_in[1];
    const float* proxies  = (const float*)d_in[2];
    float* out = (float*)d_out;              // [B*C] logits, then [1] loss

    char* ws = (char*)d_ws;
    unsigned short* xbf = (unsigned short*)ws;                                 // 4 MiB
    unsigned short* pbf = (unsigned short*)(ws + (size_t)B_BATCH * D_DIM * 2); // 10 MiB
    float* pos_sum = (float*)(ws + (size_t)(B_BATCH + P_PX) * D_DIM * 2);
    float* neg_sum = pos_sum + P_PX;

    hipMemsetAsync(pos_sum, 0, 2 * P_PX * sizeof(float), stream);

    norm_rows_kernel<<<B_BATCH + P_PX, 256, 0, stream>>>(
        features, proxies, (unsigned int*)xbf, (unsigned int*)pbf);

    fused_gemm_kernel<<<dim3(B_BATCH / BM, P_PX / BN), 256, 0, stream>>>(
        xbf, pbf, labels, out, pos_sum, neg_sum);

    finalize_kernel<<<1, 1024, 0, stream>>>(labels, pos_sum, neg_sum,
                                            out + (size_t)B_BATCH * C_CLS);
}

// Round 4
// 106.599 us; speedup vs baseline: 2.0200x; 1.2704x over previous
//
#include <hip/hip_runtime.h>
#include <hip/hip_bf16.h>

#define C_CLS   1000
#define U_PX    10
#define D_DIM   512
#define B_BATCH 4096
#define P_PX    (C_CLS * U_PX)     // 10000
#define ALPHA_F 32.0f
#define DELTA_F 0.1f

#define BM 256
#define BN 80        // 8 complete classes per tile; 10000/80 = 125
#define BK 64        // 128 B per LDS row, linear (global_load_lds dest)
#define SIMP 84      // padded per-wave sim row in f32

// LDS: A [256][128B] @0 (32K) + B [80][128B] @32768 (10K) = 43008 B, single buffer.
// After the K-loop, bytes 0..21503 are reused as 4 per-wave sim chunks [16][84] f32.
#define A_OFF   0
#define B_OFF   32768
#define SMEM_SZ 43008

typedef __attribute__((ext_vector_type(8))) short bf16x8;
typedef __attribute__((ext_vector_type(4))) float f32x4;

typedef __attribute__((address_space(1))) const void gv_t;
typedef __attribute__((address_space(3))) void lv_t;

__device__ __forceinline__ void gload_lds16(const void* g, void* lds) {
    __builtin_amdgcn_global_load_lds((gv_t*)g, (lv_t*)lds, 16, 0, 0);
}

__device__ __forceinline__ unsigned int f2bf(float f) {
    union { float f; unsigned u; } c; c.f = f;
    unsigned u = c.u;
    return (u + 0x7FFF + ((u >> 16) & 1)) >> 16;   // RN-even
}

// ---------- row L2-normalize f32 -> bf16, one wave per row, no LDS ----------
__global__ __launch_bounds__(256) void norm_rows_kernel(const float* __restrict__ feat,
                                                        const float* __restrict__ prox,
                                                        unsigned int* __restrict__ xout,
                                                        unsigned int* __restrict__ pout) {
    const int wid  = threadIdx.x >> 6;
    const int lane = threadIdx.x & 63;
    int row = blockIdx.x * 4 + wid;
    const float* in;
    unsigned int* out;
    if (row < B_BATCH) { in = feat + (size_t)row * D_DIM;   out = xout + (size_t)row * (D_DIM / 2); }
    else { row -= B_BATCH; in = prox + (size_t)row * D_DIM; out = pout + (size_t)row * (D_DIM / 2); }
    const float4 v0 = reinterpret_cast<const float4*>(in)[lane * 2];
    const float4 v1 = reinterpret_cast<const float4*>(in)[lane * 2 + 1];
    float ss = v0.x*v0.x + v0.y*v0.y + v0.z*v0.z + v0.w*v0.w
             + v1.x*v1.x + v1.y*v1.y + v1.z*v1.z + v1.w*v1.w;
    #pragma unroll
    for (int off = 1; off < 64; off <<= 1) ss += __shfl_xor(ss, off, 64);
    const float inv = 1.0f / fmaxf(sqrtf(ss), 1e-12f);
    uint4 o;
    o.x = f2bf(v0.x * inv) | (f2bf(v0.y * inv) << 16);
    o.y = f2bf(v0.z * inv) | (f2bf(v0.w * inv) << 16);
    o.z = f2bf(v1.x * inv) | (f2bf(v1.y * inv) << 16);
    o.w = f2bf(v1.z * inv) | (f2bf(v1.w * inv) << 16);
    *reinterpret_cast<uint4*>(out + lane * 4) = o;
}

// ---------- fused GEMM + logits + loss partials ----------
__global__ __launch_bounds__(256, 3) void fused_gemm_kernel(
    const unsigned short* __restrict__ xbf,   // [B][D] normalized bf16
    const unsigned short* __restrict__ pbf,   // [P][D] normalized bf16
    const int*            __restrict__ labels,
    float*                __restrict__ logits,  // [B][C]
    double*               __restrict__ pos_sum, // [P]
    double*               __restrict__ neg_sum) // [P]
{
    __shared__ __align__(16) char smem[SMEM_SZ];
    __shared__ int lab_lds[BM];

    const int t    = threadIdx.x;
    const int m0   = blockIdx.x * BM;
    const int n0   = blockIdx.y * BN;
    const int wid  = t >> 6;
    const int lane = t & 63;
    const int l15  = lane & 15;
    const int kgrp = lane >> 4;          // 0..3

    if (t < BM) lab_lds[t] = labels[m0 + t];

    // source pre-swizzle for linear global_load_lds dest (rule #21):
    // within each 1KiB chunk (8 rows of 128B), lane l writes LDS (row=l>>3, c16=l&7)
    // and must fetch global chunk (l&7) ^ (l>>3)
    const int srow = lane >> 3;                  // 0..7 within chunk
    const int scol = (lane & 7) ^ srow;          // swizzled 16B-chunk index

    // read-side swizzled K-offsets, loop-invariant: ((kk8*4+kgrp) ^ (l15&7)) << 4
    const int koff0 = ((kgrp    ) ^ (l15 & 7)) << 4;
    const int koff1 = ((kgrp + 4) ^ (l15 & 7)) << 4;

    f32x4 acc[4][5];
    #pragma unroll
    for (int m = 0; m < 4; ++m)
        #pragma unroll
        for (int n = 0; n < 5; ++n) acc[m][n] = (f32x4){0.f, 0.f, 0.f, 0.f};

    for (int ks = 0; ks < D_DIM / BK; ++ks) {
        const int kbase = ks * BK;
        // ---- stage: A 32 chunks (8 iters/wave), B 10 chunks ----
        #pragma unroll
        for (int c = wid; c < 32; c += 4)
            gload_lds16(xbf + (size_t)(m0 + c * 8 + srow) * D_DIM + kbase + scol * 8,
                        smem + A_OFF + c * 1024);
        for (int c = wid; c < 10; c += 4)
            gload_lds16(pbf + (size_t)(n0 + c * 8 + srow) * D_DIM + kbase + scol * 8,
                        smem + B_OFF + c * 1024);
        __syncthreads();   // drains vmcnt(0): tile staged
        // ---- compute: 40 MFMA / wave ----
        #pragma unroll
        for (int kk8 = 0; kk8 < 2; ++kk8) {
            const int koff = kk8 ? koff1 : koff0;
            bf16x8 b[5];
            #pragma unroll
            for (int n = 0; n < 5; ++n)
                b[n] = *reinterpret_cast<const bf16x8*>(smem + B_OFF + (n * 16 + l15) * 128 + koff);
            #pragma unroll
            for (int m = 0; m < 4; ++m) {
                const bf16x8 a = *reinterpret_cast<const bf16x8*>(
                    smem + A_OFF + (wid * 64 + m * 16 + l15) * 128 + koff);
                #pragma unroll
                for (int n = 0; n < 5; ++n)
                    acc[m][n] = __builtin_amdgcn_mfma_f32_16x16x32_bf16(a, b[n], acc[m][n], 0, 0, 0);
            }
        }
        __syncthreads();   // all reads done before next stage overwrites
    }

    // ---- loss partials fully in-register ----
    // lane holds sim(row = wid*64 + m*16 + kgrp*4 + r, col = n*16 + l15) in acc[m][n][r]
    {
        int labv[16];
        #pragma unroll
        for (int m = 0; m < 4; ++m)
            #pragma unroll
            for (int r = 0; r < 4; ++r)
                labv[m * 4 + r] = lab_lds[wid * 64 + m * 16 + kgrp * 4 + r];
        #pragma unroll
        for (int n = 0; n < 5; ++n) {
            const int col = n * 16 + l15;
            const int cls = (n0 + col) / U_PX;
            float pos = 0.f, neg = 0.f;
            #pragma unroll
            for (int m = 0; m < 4; ++m)
                #pragma unroll
                for (int r = 0; r < 4; ++r) {
                    const float s = acc[m][n][r];
                    const bool isp = (labv[m * 4 + r] == cls);
                    const float e = __expf(isp ? (-ALPHA_F * (s - DELTA_F))
                                               : ( ALPHA_F * (s + DELTA_F)));
                    if (isp) pos += e; else neg += e;
                }
            // reduce across the 4 kgrp lanes holding the same column (xor 16, 32)
            pos += __shfl_xor(pos, 16, 64); pos += __shfl_xor(pos, 32, 64);
            neg += __shfl_xor(neg, 16, 64); neg += __shfl_xor(neg, 32, 64);
            if (lane < 16) {
                atomicAdd(&neg_sum[n0 + col], (double)neg);
                if (pos != 0.f) atomicAdd(&pos_sum[n0 + col], (double)pos);
            }
        }
    }

    // ---- logits per wave (rows are wave-private; K-loop's final barrier already passed) ----
    float* simw = reinterpret_cast<float*>(smem) + wid * (16 * SIMP);   // 5376 B/wave
    #pragma unroll
    for (int m = 0; m < 4; ++m) {
        #pragma unroll
        for (int n = 0; n < 5; ++n)
            #pragma unroll
            for (int r = 0; r < 4; ++r)
                simw[(kgrp * 4 + r) * SIMP + n * 16 + l15] = acc[m][n][r];
        // wave-internal RAW on LDS: compiler inserts lgkmcnt; wave executes in lockstep
        #pragma unroll
        for (int it = 0; it < 2; ++it) {
            const int j   = lane + it * 64;       // 0..127
            const int r   = j >> 3;               // row within 16
            const int c   = j & 7;                // class within 8
            const float* s = simw + r * SIMP + c * U_PX;
            float wsum = 0.f, wssum = 0.f;
            #pragma unroll
            for (int u = 0; u < U_PX; ++u) {
                const float sv = s[u];
                const float e = __expf(sv);       // |s|<=1: no max-shift needed
                wsum += e; wssum += e * sv;
            }
            logits[(size_t)(m0 + wid * 64 + m * 16 + r) * C_CLS + (n0 / U_PX + c)] = wssum / wsum;
        }
        __builtin_amdgcn_s_waitcnt(0);            // lgkm drained before overwriting simw
    }
}

// ---------- finalize: histogram -> has_pos, log1p reductions -> scalar loss ----------
__global__ __launch_bounds__(1024) void finalize_kernel(
    const int*    __restrict__ labels,
    const double* __restrict__ pos_sum,
    const double* __restrict__ neg_sum,
    float*        __restrict__ out_loss)
{
    __shared__ int    hist[C_CLS];
    __shared__ double sp[1024], sn[1024];
    __shared__ int    sc[1024];
    const int t = threadIdx.x;
    for (int i = t; i < C_CLS; i += 1024) hist[i] = 0;
    __syncthreads();
    for (int i = t; i < B_BATCH; i += 1024) atomicAdd(&hist[labels[i]], 1);
    __syncthreads();
    double pAcc = 0.0, nAcc = 0.0; int cnt = 0;
    for (int p = t; p < P_PX; p += 1024) {
        nAcc += log1p(neg_sum[p]);
        if (hist[p / U_PX] > 0) { pAcc += log1p(pos_sum[p]); cnt++; }
    }
    sp[t] = pAcc; sn[t] = nAcc; sc[t] = cnt;
    __syncthreads();
    for (int s = 512; s > 0; s >>= 1) {
        if (t < s) { sp[t] += sp[t + s]; sn[t] += sn[t + s]; sc[t] += sc[t + s]; }
        __syncthreads();
    }
    if (t == 0)
        out_loss[0] = (float)(sp[0] / (double)max(sc[0], 1) + sn[0] / (double)P_PX);
}

extern "C" void kernel_launch(void* const* d_in, const int* in_sizes, int n_in,
                              void* d_out, int out_size, void* d_ws, size_t ws_size,
                              hipStream_t stream) {
    const float* features = (const float*)d_in[0];
    const int*   labels   = (const int*)d_in[1];
    const float* proxies  = (const float*)d_in[2];
    float* out = (float*)d_out;              // [B*C] logits, then [1] loss

    char* ws = (char*)d_ws;
    unsigned short* xbf = (unsigned short*)ws;                                 // 4 MiB
    unsigned short* pbf = (unsigned short*)(ws + (size_t)B_BATCH * D_DIM * 2); // 10 MiB
    double* pos_sum = (double*)(ws + (size_t)(B_BATCH + P_PX) * D_DIM * 2);
    double* neg_sum = pos_sum + P_PX;

    hipMemsetAsync(pos_sum, 0, 2 * P_PX * sizeof(double), stream);

    norm_rows_kernel<<<(B_BATCH + P_PX) / 4, 256, 0, stream>>>(
        features, proxies, (unsigned int*)xbf, (unsigned int*)pbf);

    fused_gemm_kernel<<<dim3(B_BATCH / BM, P_PX / BN), 256, 0, stream>>>(
        xbf, pbf, labels, out, pos_sum, neg_sum);

    finalize_kernel<<<1, 1024, 0, stream>>>(labels, pos_sum, neg_sum,
                                            out + (size_t)B_BATCH * C_CLS);
}